// Round 8
// baseline (693.348 us; speedup 1.0000x reference)
//
#include <hip/hip_runtime.h>

#define L 50
#define NA 120
#define NB 8
#define NPIX 2500
#define NFREQ 51
#define NFULL 100
#define IST 52                 // F1 global inner stride (16B-aligned)
#define ISPEC (NFULL * IST)    // 5200 float2 per F1 spectrum
#define PST 53                 // LDS inner stride (bank-conflict break)
#define ASTEP 0.026179938779914944f   // pi/120
#define PHI   0.06283185307179586f    // 2*pi/100

// workspace layout in floats
#define OFF_REC  0                    // 8*2*2500 = 40000
#define OFF_LIG  40000                // 40000
#define OFF_F1   80000                // 16 * 5200 f2 = 166400 floats
#define OFF_P2   246400               // 960 * 6000 f2 = 11520000 floats
#define OFF_PVAL 11766400             // 960
#define OFF_PIDX 11767360             // 960

#define CROT(wx, wy, sx, sy) { float nx_ = fmaf(wx, sx, -(wy) * (sy)); \
                               float ny_ = fmaf(wx, sy,  (wy) * (sx)); \
                               wx = nx_; wy = ny_; }

// ---------------- conv 3x3 (SAME) + bias; ligand channels combined with
// scorer weights (linearity: rotate/FFT commute with the real combine) ------
__global__ __launch_bounds__(256) void k_conv(
    const float* __restrict__ rec, const float* __restrict__ lig,
    const float* __restrict__ cw, const float* __restrict__ cb,
    const float* __restrict__ sw,
    float* __restrict__ rec_feat, float* __restrict__ lig_comb) {
  int t = blockIdx.x * blockDim.x + threadIdx.x;
  if (t >= NB * NPIX) return;
  int b = t / NPIX, p = t % NPIX;
  int i = p / L, j = p % L;
  float r0 = cb[0], r1 = cb[1], l0 = cb[0], l1 = cb[1];
  for (int di = 0; di < 3; ++di) {
    int ii = i + di - 1;
    if (ii < 0 || ii >= L) continue;
    for (int dj = 0; dj < 3; ++dj) {
      int jj = j + dj - 1;
      if (jj < 0 || jj >= L) continue;
      float w0 = cw[di * 3 + dj], w1 = cw[9 + di * 3 + dj];
      float xv = rec[b * NPIX + ii * L + jj];
      float yv = lig[b * NPIX + ii * L + jj];
      r0 += w0 * xv; r1 += w1 * xv;
      l0 += w0 * yv; l1 += w1 * yv;
    }
  }
  rec_feat[(b * 2 + 0) * NPIX + p] = r0;
  rec_feat[(b * 2 + 1) * NPIX + p] = r1;
  lig_comb[(b * 2 + 0) * NPIX + p] = sw[0] * l0 + sw[1] * l1;
  lig_comb[(b * 2 + 1) * NPIX + p] = sw[2] * l0 + sw[3] * l1;
}

// ---- rowDFT: Arow[r][k] = sum_c img[r][c] e^{-i*PHI*k*c}; 10 rows/thread ---
__device__ __forceinline__ void rowdft53(const float* img, float2* Arow, int tid) {
  if (tid < 255) {
    const int kR = tid % 51, rgR = tid / 51;   // rows rgR + 5t, t<10
    float are[10], aim[10];
#pragma unroll
    for (int t = 0; t < 10; ++t) { are[t] = 0.f; aim[t] = 0.f; }
    float stx, sty;
    sincosf(PHI * (float)kR, &sty, &stx); sty = -sty;
    for (int half = 0; half < 2; ++half) {
      int u0 = half ? 6 : 0, u1 = half ? 13 : 6;
      float wx, wy;
      int t0 = half ? (24 * kR) % 100 : 0;
      sincosf(PHI * (float)t0, &wy, &wx); wy = -wy;
      for (int u = u0; u < u1; ++u) {
        float4 q[10];
#pragma unroll
        for (int t = 0; t < 10; ++t)
          q[t] = *(const float4*)(img + (rgR + 5 * t) * 52 + 4 * u);
#pragma unroll
        for (int v = 0; v < 4; ++v) {
#pragma unroll
          for (int t = 0; t < 10; ++t) {
            float val = (v == 0) ? q[t].x : (v == 1) ? q[t].y : (v == 2) ? q[t].z : q[t].w;
            are[t] = fmaf(val, wx, are[t]);
            aim[t] = fmaf(val, wy, aim[t]);
          }
          CROT(wx, wy, stx, sty);
        }
      }
    }
#pragma unroll
    for (int t = 0; t < 10; ++t)
      Arow[(rgR + 5 * t) * PST + kR] = make_float2(are[t], aim[t]);
  }
}

// ---------------- forward rfft2 of receptor channels: 16 images x 5 k-chunks
// per block (80 blocks -> latency hidden). colDFT over 250 lanes, <=3 cols. --
__global__ __launch_bounds__(256, 3) void k_fwd_rec(
    const float* __restrict__ src, float2* __restrict__ F1w) {
  __shared__ __align__(16) float img[50 * 52];
  __shared__ __align__(16) float2 Arow[50 * PST + 8];
  const int tid = threadIdx.x;
  const int im = blockIdx.x % 16, kcB = blockIdx.x / 16;   // 5 chunks
  const int k0 = (kcB == 0) ? 0 : 11 + 10 * (kcB - 1);
  const int W  = (kcB == 0) ? 11 : 10;
  for (int o = tid; o < 50 * 52; o += 256) {
    int i = o / 52, j = o - i * 52;
    img[o] = (j < 50) ? src[im * NPIX + i * 50 + j] : 0.f;
  }
  __syncthreads();
  rowdft53(img, Arow, tid);
  __syncthreads();
  if (tid < 250) {
    const int mp = tid % 50, sub = tid / 50;
    int c0, cw;
    if (kcB == 0) { cw = (sub == 0) ? 3 : 2; c0 = (sub == 0) ? 0 : 1 + 2 * sub; }
    else          { cw = 2; c0 = 2 * sub; }
    float Ex[3], Ey[3], Ox[3], Oy[3];
#pragma unroll
    for (int i = 0; i < 3; ++i) { Ex[i] = 0.f; Ey[i] = 0.f; Ox[i] = 0.f; Oy[i] = 0.f; }
    float s2x, s2y;
    sincosf(PHI * (float)((2 * mp) % 100), &s2y, &s2x); s2y = -s2y;
    { float wx = 1.f, wy = 0.f;
      for (int s = 0; s < 25; ++s) {
        const float2* ap = Arow + (2 * s) * PST + k0 + c0;
#pragma unroll
        for (int i = 0; i < 3; ++i) if (i < cw) {
          float2 q = ap[i];
          Ex[i] = fmaf(q.x, wx, fmaf(-q.y, wy, Ex[i]));
          Ey[i] = fmaf(q.x, wy, fmaf( q.y, wx, Ey[i]));
        }
        CROT(wx, wy, s2x, s2y);
      } }
    { float wx, wy;
      sincosf(PHI * (float)mp, &wy, &wx); wy = -wy;
      for (int s = 0; s < 25; ++s) {
        const float2* ap = Arow + (2 * s + 1) * PST + k0 + c0;
#pragma unroll
        for (int i = 0; i < 3; ++i) if (i < cw) {
          float2 q = ap[i];
          Ox[i] = fmaf(q.x, wx, fmaf(-q.y, wy, Ox[i]));
          Oy[i] = fmaf(q.x, wy, fmaf( q.y, wx, Oy[i]));
        }
        CROT(wx, wy, s2x, s2y);
      } }
    float2* d0 = F1w + (size_t)im * ISPEC + mp * IST + k0 + c0;
    float2* d1 = d0 + 50 * IST;
#pragma unroll
    for (int i = 0; i < 3; ++i)
      if (i < cw) {
        d0[i] = make_float2(Ex[i] + Ox[i], Ey[i] + Oy[i]);
        d1[i] = make_float2(Ex[i] - Ox[i], Ey[i] - Oy[i]);
      }
  }
}

// ---------------- per-(angle,batch): rotate(x2) -> rowDFT(x2, both spectra
// resident) -> colDFT radix-2 + product, W=6, packed coalesced P write ------
// P2 layout: [ab][vlane 0..499][12 float2]; vlane v owns mp=v%50, k0=5*(v/50),
// slots 0..5 = P[mp][k0..k0+5], slots 6..11 = P[mp+50][k0..k0+5].
__global__ __launch_bounds__(256, 3) void k_fwd_prod(
    const float* __restrict__ lig_comb, const float2* __restrict__ F1,
    float2* __restrict__ P2) {
  __shared__ __align__(16) float img[50 * 52];          // 10.4 KB
  __shared__ __align__(16) float2 Arow[2][50 * PST];    // 42.4 KB
  const int tid = threadIdx.x;
  const int ab = blockIdx.x, a = ab / NB, b = ab % NB;
  float sa, ca; sincosf((float)a * ASTEP, &sa, &ca);

  for (int f = 0; f < 2; ++f) {
    const float* src = lig_comb + (b * 2 + f) * NPIX;
    for (int o = tid; o < 50 * 52; o += 256) {
      int i = o / 52, j = o - i * 52;
      float acc = 0.f;
      if (j < 50) {
        float gx = fmaf((float)j, 2.0f / 49.0f, -1.0f);
        float gy = fmaf((float)i, 2.0f / 49.0f, -1.0f);
        float ix = (ca * gx + sa * gy + 1.0f) * 24.5f;
        float iy = (ca * gy - sa * gx + 1.0f) * 24.5f;
        float x0 = floorf(ix), y0 = floorf(iy);
#pragma unroll
        for (int dy = 0; dy < 2; ++dy)
#pragma unroll
          for (int dx = 0; dx < 2; ++dx) {
            float xc = x0 + dx, yc = y0 + dy;
            float w = (1.0f - fabsf(ix - xc)) * (1.0f - fabsf(iy - yc));
            bool valid = (xc >= 0.f) && (xc < 50.f) && (yc >= 0.f) && (yc < 50.f);
            int xi = (int)fminf(fmaxf(xc, 0.f), 49.f);
            int yi = (int)fminf(fmaxf(yc, 0.f), 49.f);
            acc += valid ? w * src[yi * L + xi] : 0.f;
          }
      }
      img[o] = acc;
    }
    __syncthreads();
    rowdft53(img, Arow[f], tid);
    __syncthreads();
  }

  // colDFT + product, 2 passes x 250 lanes, W=6 (phase-local 48-float accs)
  for (int pass = 0; pass < 2; ++pass) {
    if (tid < 250) {
      const int v = pass * 250 + tid;
      const int mp = v % 50, c = v / 50;
      const int k0 = 5 * c;
      float E0x[6], E0y[6], O0x[6], O0y[6];
      float E1x[6], E1y[6], O1x[6], O1y[6];
#pragma unroll
      for (int i = 0; i < 6; ++i) {
        E0x[i] = 0.f; E0y[i] = 0.f; O0x[i] = 0.f; O0y[i] = 0.f;
        E1x[i] = 0.f; E1y[i] = 0.f; O1x[i] = 0.f; O1y[i] = 0.f;
      }
      float s2x, s2y;
      sincosf(PHI * (float)((2 * mp) % 100), &s2y, &s2x); s2y = -s2y;
      { float wx = 1.f, wy = 0.f;           // even rows
        for (int s = 0; s < 25; ++s) {
          const float2* a0 = &Arow[0][(2 * s) * PST + k0];
          const float2* a1 = &Arow[1][(2 * s) * PST + k0];
#pragma unroll
          for (int i = 0; i < 6; ++i) {
            float2 q0 = a0[i], q1 = a1[i];
            E0x[i] = fmaf(q0.x, wx, fmaf(-q0.y, wy, E0x[i]));
            E0y[i] = fmaf(q0.x, wy, fmaf( q0.y, wx, E0y[i]));
            E1x[i] = fmaf(q1.x, wx, fmaf(-q1.y, wy, E1x[i]));
            E1y[i] = fmaf(q1.x, wy, fmaf( q1.y, wx, E1y[i]));
          }
          CROT(wx, wy, s2x, s2y);
        } }
      { float wx, wy;                       // odd rows
        sincosf(PHI * (float)mp, &wy, &wx); wy = -wy;
        for (int s = 0; s < 25; ++s) {
          const float2* a0 = &Arow[0][(2 * s + 1) * PST + k0];
          const float2* a1 = &Arow[1][(2 * s + 1) * PST + k0];
#pragma unroll
          for (int i = 0; i < 6; ++i) {
            float2 q0 = a0[i], q1 = a1[i];
            O0x[i] = fmaf(q0.x, wx, fmaf(-q0.y, wy, O0x[i]));
            O0y[i] = fmaf(q0.x, wy, fmaf( q0.y, wx, O0y[i]));
            O1x[i] = fmaf(q1.x, wx, fmaf(-q1.y, wy, O1x[i]));
            O1y[i] = fmaf(q1.x, wy, fmaf( q1.y, wx, O1y[i]));
          }
          CROT(wx, wy, s2x, s2y);
        } }
      const float2* F0a = F1 + (size_t)(b * 2 + 0) * ISPEC + mp * IST + k0;
      const float2* F0b = F0a + 50 * IST;
      const float2* F1a = F1 + (size_t)(b * 2 + 1) * ISPEC + mp * IST + k0;
      const float2* F1b = F1a + 50 * IST;
      float2 tmp[12];
#pragma unroll
      for (int i = 0; i < 6; ++i) {
        float gm0x = E0x[i] + O0x[i], gm0y = E0y[i] + O0y[i];
        float gp0x = E0x[i] - O0x[i], gp0y = E0y[i] - O0y[i];
        float gm1x = E1x[i] + O1x[i], gm1y = E1y[i] + O1y[i];
        float gp1x = E1x[i] - O1x[i], gp1y = E1y[i] - O1y[i];
        float2 A0 = F0a[i], B0 = F0b[i], A1 = F1a[i], B1 = F1b[i];
        tmp[i] = make_float2(
            fmaf(A0.x, gm0x, fmaf(A0.y, gm0y, fmaf(A1.x, gm1x, A1.y * gm1y))),
            fmaf(A0.y, gm0x, fmaf(-A0.x, gm0y, fmaf(A1.y, gm1x, -A1.x * gm1y))));
        tmp[6 + i] = make_float2(
            fmaf(B0.x, gp0x, fmaf(B0.y, gp0y, fmaf(B1.x, gp1x, B1.y * gp1y))),
            fmaf(B0.y, gp0x, fmaf(-B0.x, gp0y, fmaf(B1.y, gp1x, -B1.x * gp1y))));
      }
      float4* dst = (float4*)(P2 + (size_t)ab * 6000 + v * 12);
#pragma unroll
      for (int j = 0; j < 6; ++j)
        dst[j] = make_float4(tmp[2 * j].x, tmp[2 * j].y, tmp[2 * j + 1].x, tmp[2 * j + 1].y);
    }
  }
}

// ---------------- inverse (radix-2 both stages, 250 lanes) + argmax --------
__global__ __launch_bounds__(256, 3) void k_inv_argmax(
    const float2* __restrict__ P2, float* __restrict__ pval,
    int* __restrict__ pidx) {
  __shared__ __align__(16) float2 Pl[100 * PST];   // P[m][k]; later T[k][100]
  __shared__ float rv[256];
  __shared__ int ri[256];
  const int tid = threadIdx.x, ab = blockIdx.x;

  // un-pack packed P into Pl[m*PST + k]
  if (tid < 250) {
#pragma unroll
    for (int h = 0; h < 2; ++h) {
      int v = h * 250 + tid;
      int mp = v % 50, c = v / 50, k0p = 5 * c;
      const float4* s4 = (const float4*)(P2 + (size_t)ab * 6000 + v * 12);
      float2 tv[12];
#pragma unroll
      for (int j = 0; j < 6; ++j) {
        float4 q = s4[j];
        tv[2 * j] = make_float2(q.x, q.y);
        tv[2 * j + 1] = make_float2(q.z, q.w);
      }
#pragma unroll
      for (int i = 0; i < 6; ++i) {
        Pl[mp * PST + k0p + i] = tv[i];
        Pl[(mp + 50) * PST + k0p + i] = tv[6 + i];
      }
    }
  }
  __syncthreads();

  // stage 1: T[r][k] = sum_m P[m][k] e^{+i*PHI*m*r}; radix-2 pairs (r, r+50);
  // 250 lanes: (rp, kc) with chunk widths 11,10,10,10,10
  const int rp = tid % 50, kc = tid / 50;
  const int k0 = (kc == 0) ? 0 : 11 + 10 * (kc - 1);
  const int W  = (kc == 0) ? 11 : 10;
  float Ex[11], Ey[11], Ox[11], Oy[11];
  if (tid < 250) {
#pragma unroll
    for (int i = 0; i < 11; ++i) { Ex[i] = 0.f; Ey[i] = 0.f; Ox[i] = 0.f; Oy[i] = 0.f; }
    float stx, sty;
    sincosf(PHI * (float)((2 * rp) % 100), &sty, &stx);   // step e^{+2i phi r}
    { float wx = 1.f, wy = 0.f;
      for (int s = 0; s < 50; ++s) {
        if (s == 25) { wx = (rp & 1) ? -1.f : 1.f; wy = 0.f; }   // exact renorm
        const float2* pp = Pl + (2 * s) * PST + k0;
#pragma unroll
        for (int i = 0; i < 11; ++i) if (i < W) {
          float2 q = pp[i];
          Ex[i] = fmaf(q.x, wx, fmaf(-q.y, wy, Ex[i]));
          Ey[i] = fmaf(q.x, wy, fmaf( q.y, wx, Ey[i]));
        }
        CROT(wx, wy, stx, sty);
      } }
    { float wx, wy;
      sincosf(PHI * (float)rp, &wy, &wx);                  // e^{+i phi r}
      for (int s = 0; s < 50; ++s) {
        if (s == 25) { int t0 = (51 * rp) % 100; sincosf(PHI * (float)t0, &wy, &wx); }
        const float2* pp = Pl + (2 * s + 1) * PST + k0;
#pragma unroll
        for (int i = 0; i < 11; ++i) if (i < W) {
          float2 q = pp[i];
          Ox[i] = fmaf(q.x, wx, fmaf(-q.y, wy, Ox[i]));
          Oy[i] = fmaf(q.x, wy, fmaf( q.y, wx, Oy[i]));
        }
        CROT(wx, wy, stx, sty);
      } }
  }
  __syncthreads();   // all P reads complete
  if (tid < 250) {
#pragma unroll
    for (int i = 0; i < 11; ++i)
      if (i < W) {
        int k = k0 + i;
        Pl[k * NFULL + rp]      = make_float2(Ex[i] + Ox[i], Ey[i] + Oy[i]);
        Pl[k * NFULL + rp + 50] = make_float2(Ex[i] - Ox[i], Ey[i] - Oy[i]);
      }
  }
  __syncthreads();   // T[k][r] ready (transposed)

  // stage 2: radix-2 pairs (c, c+50) via even/odd k; 250 lanes (cp, kc*20)
  float best = -3.4e38f;
  int bidx = 0x7fffffff;
  if (tid < 250) {
    const int cp = rp;
    const int r0 = kc * 20;
    float e20[20], o20[20];
#pragma unroll
    for (int i = 0; i < 20; ++i) { e20[i] = 0.f; o20[i] = 0.f; }
    float q2x, q2y;
    sincosf(PHI * (float)((2 * cp) % 100), &q2y, &q2x);
    { float wx = q2x, wy = q2y;             // k=2
      for (int s = 1; s < 25; ++s) {
        const float2* tp = Pl + (2 * s) * NFULL + r0;
#pragma unroll
        for (int i = 0; i < 20; ++i) {
          float2 q = tp[i];
          e20[i] = fmaf(q.x, wx, fmaf(-q.y, wy, e20[i]));
        }
        CROT(wx, wy, q2x, q2y);
      } }
    { float wx, wy;
      sincosf(PHI * (float)cp, &wy, &wx);   // k=1
      for (int s = 0; s < 25; ++s) {
        const float2* tp = Pl + (2 * s + 1) * NFULL + r0;
#pragma unroll
        for (int i = 0; i < 20; ++i) {
          float2 q = tp[i];
          o20[i] = fmaf(q.x, wx, fmaf(-q.y, wy, o20[i]));
        }
        CROT(wx, wy, q2x, q2y);
      } }
    float sgn = (cp & 1) ? -1.f : 1.f;
    const float2* T0  = Pl + r0;
    const float2* T50 = Pl + 50 * NFULL + r0;
#pragma unroll
    for (int i = 0; i < 20; ++i) {
      int r = r0 + i;
      float base = T0[i].x + sgn * T50[i].x;
      float X0 = fmaf(2.f, e20[i] + o20[i], base);   // c = cp
      float X1 = fmaf(2.f, e20[i] - o20[i], base);   // c = cp + 50
      int xs = r + 50; if (xs >= 100) xs -= 100;
      int f0 = xs * 100 + cp + 50, f1 = xs * 100 + cp;
      if (X0 > best || (X0 == best && f0 < bidx)) { best = X0; bidx = f0; }
      if (X1 > best || (X1 == best && f1 < bidx)) { best = X1; bidx = f1; }
    }
  }
  rv[tid] = best; ri[tid] = bidx;
  __syncthreads();
  for (int s = 128; s > 0; s >>= 1) {
    if (tid < s) {
      float ov = rv[tid + s]; int oi = ri[tid + s];
      if (ov > rv[tid] || (ov == rv[tid] && oi < ri[tid])) { rv[tid] = ov; ri[tid] = oi; }
    }
    __syncthreads();
  }
  if (tid == 0) { pval[ab] = rv[0]; pidx[ab] = (ab / NB) * 10000 + ri[0]; }
}

// ---------------- final per-batch reduction over 120 angles ----------------
__global__ void k_final(const float* __restrict__ pval,
                        const int* __restrict__ pidx, float* __restrict__ out) {
  int b = threadIdx.x;
  if (b >= NB) return;
  float best = -3.4e38f; int bidx = 0x7fffffff;
  for (int a = 0; a < NA; ++a) {
    float v = pval[a * NB + b]; int ix = pidx[a * NB + b];
    if (v > best || (v == best && ix < bidx)) { best = v; bidx = ix; }
  }
  int a = bidx / 10000, rr = bidx % 10000, x = rr / NFULL, y = rr % NFULL;
  out[b] = a * ASTEP;
  out[NB + b * 2 + 0] = (float)(x - L);
  out[NB + b * 2 + 1] = (float)(y - L);
}

extern "C" void kernel_launch(void* const* d_in, const int* in_sizes, int n_in,
                              void* d_out, int out_size, void* d_ws, size_t ws_size,
                              hipStream_t stream) {
  const float* receptor = (const float*)d_in[0];
  const float* ligand   = (const float*)d_in[1];
  const float* conv_w   = (const float*)d_in[2];
  const float* conv_b   = (const float*)d_in[3];
  const float* scorer_w = (const float*)d_in[4];
  // scorer_b (d_in[5]) is argmax-invariant: unused.
  float* ws = (float*)d_ws;
  float* rec_feat = ws + OFF_REC;
  float* lig_comb = ws + OFF_LIG;
  float2* F1      = (float2*)(ws + OFF_F1);
  float2* P2      = (float2*)(ws + OFF_P2);
  float* pval     = ws + OFF_PVAL;
  int*   pidx     = (int*)(ws + OFF_PIDX);
  float* out      = (float*)d_out;

  k_conv<<<(NB * NPIX + 255) / 256, 256, 0, stream>>>(
      receptor, ligand, conv_w, conv_b, scorer_w, rec_feat, lig_comb);
  k_fwd_rec<<<80, 256, 0, stream>>>(rec_feat, F1);
  k_fwd_prod<<<NA * NB, 256, 0, stream>>>(lig_comb, F1, P2);
  k_inv_argmax<<<NA * NB, 256, 0, stream>>>(P2, pval, pidx);
  k_final<<<1, 64, 0, stream>>>(pval, pidx, out);
}

// Round 9
// 297.950 us; speedup vs baseline: 2.3271x; 2.3271x over previous
//
#include <hip/hip_runtime.h>

#define L 50
#define NA 120
#define NB 8
#define NPIX 2500
#define NFREQ 51
#define NFULL 100
#define IST 52                 // F1 global inner stride (16B-aligned)
#define ISPEC (NFULL * IST)    // 5200 float2 per F1 spectrum
#define PST 53                 // LDS inner stride (bank-conflict break)
#define ASTEP 0.026179938779914944f   // pi/120
#define PHI   0.06283185307179586f    // 2*pi/100

// workspace layout in floats
#define OFF_REC  0                    // 8*2*2500 = 40000
#define OFF_LIG  40000                // 40000
#define OFF_F1   80000                // 16 * 5200 f2 = 166400 floats
#define OFF_P2   246400               // 960 * 6000 f2 = 11520000 floats
#define OFF_PVAL 11766400             // 960
#define OFF_PIDX 11767360             // 960

#define CROT(wx, wy, sx, sy) { float nx_ = fmaf(wx, sx, -(wy) * (sy)); \
                               float ny_ = fmaf(wx, sy,  (wy) * (sx)); \
                               wx = nx_; wy = ny_; }

// ---------------- conv 3x3 (SAME) + bias; ligand channels combined with
// scorer weights (linearity: rotate/FFT commute with the real combine) ------
__global__ __launch_bounds__(256) void k_conv(
    const float* __restrict__ rec, const float* __restrict__ lig,
    const float* __restrict__ cw, const float* __restrict__ cb,
    const float* __restrict__ sw,
    float* __restrict__ rec_feat, float* __restrict__ lig_comb) {
  int t = blockIdx.x * blockDim.x + threadIdx.x;
  if (t >= NB * NPIX) return;
  int b = t / NPIX, p = t % NPIX;
  int i = p / L, j = p % L;
  float r0 = cb[0], r1 = cb[1], l0 = cb[0], l1 = cb[1];
  for (int di = 0; di < 3; ++di) {
    int ii = i + di - 1;
    if (ii < 0 || ii >= L) continue;
    for (int dj = 0; dj < 3; ++dj) {
      int jj = j + dj - 1;
      if (jj < 0 || jj >= L) continue;
      float w0 = cw[di * 3 + dj], w1 = cw[9 + di * 3 + dj];
      float xv = rec[b * NPIX + ii * L + jj];
      float yv = lig[b * NPIX + ii * L + jj];
      r0 += w0 * xv; r1 += w1 * xv;
      l0 += w0 * yv; l1 += w1 * yv;
    }
  }
  rec_feat[(b * 2 + 0) * NPIX + p] = r0;
  rec_feat[(b * 2 + 1) * NPIX + p] = r1;
  lig_comb[(b * 2 + 0) * NPIX + p] = sw[0] * l0 + sw[1] * l1;
  lig_comb[(b * 2 + 1) * NPIX + p] = sw[2] * l0 + sw[3] * l1;
}

// ---- rowDFT: Arow[r][k] = sum_c img[r][c] e^{-i*PHI*k*c}; 10 rows/thread ---
__device__ __forceinline__ void rowdft53(const float* img, float2* Arow, int tid) {
  if (tid < 255) {
    const int kR = tid % 51, rgR = tid / 51;   // rows rgR + 5t, t<10
    float are[10], aim[10];
#pragma unroll
    for (int t = 0; t < 10; ++t) { are[t] = 0.f; aim[t] = 0.f; }
    float stx, sty;
    sincosf(PHI * (float)kR, &sty, &stx); sty = -sty;
    for (int half = 0; half < 2; ++half) {
      int u0 = half ? 6 : 0, u1 = half ? 13 : 6;
      float wx, wy;
      int t0 = half ? (24 * kR) % 100 : 0;
      sincosf(PHI * (float)t0, &wy, &wx); wy = -wy;
      for (int u = u0; u < u1; ++u) {
        float4 q[10];
#pragma unroll
        for (int t = 0; t < 10; ++t)
          q[t] = *(const float4*)(img + (rgR + 5 * t) * 52 + 4 * u);
#pragma unroll
        for (int v = 0; v < 4; ++v) {
#pragma unroll
          for (int t = 0; t < 10; ++t) {
            float val = (v == 0) ? q[t].x : (v == 1) ? q[t].y : (v == 2) ? q[t].z : q[t].w;
            are[t] = fmaf(val, wx, are[t]);
            aim[t] = fmaf(val, wy, aim[t]);
          }
          CROT(wx, wy, stx, sty);
        }
      }
    }
#pragma unroll
    for (int t = 0; t < 10; ++t)
      Arow[(rgR + 5 * t) * PST + kR] = make_float2(are[t], aim[t]);
  }
}

// ---------------- forward rfft2 of receptor channels: 16 images x 5 k-chunks
// per block (80 blocks -> latency hidden). colDFT over 250 lanes, <=3 cols. --
__global__ __launch_bounds__(256, 3) void k_fwd_rec(
    const float* __restrict__ src, float2* __restrict__ F1w) {
  __shared__ __align__(16) float img[50 * 52];
  __shared__ __align__(16) float2 Arow[50 * PST + 8];
  const int tid = threadIdx.x;
  const int im = blockIdx.x % 16, kcB = blockIdx.x / 16;   // 5 chunks
  const int k0 = (kcB == 0) ? 0 : 11 + 10 * (kcB - 1);
  for (int o = tid; o < 50 * 52; o += 256) {
    int i = o / 52, j = o - i * 52;
    img[o] = (j < 50) ? src[im * NPIX + i * 50 + j] : 0.f;
  }
  __syncthreads();
  rowdft53(img, Arow, tid);
  __syncthreads();
  if (tid < 250) {
    const int mp = tid % 50, sub = tid / 50;
    int c0, cw;
    if (kcB == 0) { cw = (sub == 0) ? 3 : 2; c0 = (sub == 0) ? 0 : 1 + 2 * sub; }
    else          { cw = 2; c0 = 2 * sub; }
    float Ex[3], Ey[3], Ox[3], Oy[3];
#pragma unroll
    for (int i = 0; i < 3; ++i) { Ex[i] = 0.f; Ey[i] = 0.f; Ox[i] = 0.f; Oy[i] = 0.f; }
    float s2x, s2y;
    sincosf(PHI * (float)((2 * mp) % 100), &s2y, &s2x); s2y = -s2y;
    { float wx = 1.f, wy = 0.f;
      for (int s = 0; s < 25; ++s) {
        const float2* ap = Arow + (2 * s) * PST + k0 + c0;
#pragma unroll
        for (int i = 0; i < 3; ++i) {
          float2 q = ap[i];
          Ex[i] = fmaf(q.x, wx, fmaf(-q.y, wy, Ex[i]));
          Ey[i] = fmaf(q.x, wy, fmaf( q.y, wx, Ey[i]));
        }
        CROT(wx, wy, s2x, s2y);
      } }
    { float wx, wy;
      sincosf(PHI * (float)mp, &wy, &wx); wy = -wy;
      for (int s = 0; s < 25; ++s) {
        const float2* ap = Arow + (2 * s + 1) * PST + k0 + c0;
#pragma unroll
        for (int i = 0; i < 3; ++i) {
          float2 q = ap[i];
          Ox[i] = fmaf(q.x, wx, fmaf(-q.y, wy, Ox[i]));
          Oy[i] = fmaf(q.x, wy, fmaf( q.y, wx, Oy[i]));
        }
        CROT(wx, wy, s2x, s2y);
      } }
    float2* d0 = F1w + (size_t)im * ISPEC + mp * IST + k0 + c0;
    float2* d1 = d0 + 50 * IST;
#pragma unroll
    for (int i = 0; i < 3; ++i)
      if (i < cw) {
        d0[i] = make_float2(Ex[i] + Ox[i], Ey[i] + Oy[i]);
        d1[i] = make_float2(Ex[i] - Ox[i], Ey[i] - Oy[i]);
      }
  }
}

// ---------------- per-(angle,batch): rotate(x2) -> rowDFT(x2, both spectra
// resident) -> colDFT radix-2 + product, W=6, packed coalesced P write ------
// P2 layout: [ab][vlane 0..499][12 float2]; vlane v owns mp=v%50, k0=5*(v/50),
// slots 0..5 = P[mp][k0..k0+5], slots 6..11 = P[mp+50][k0..k0+5].
__global__ __launch_bounds__(256, 3) void k_fwd_prod(
    const float* __restrict__ lig_comb, const float2* __restrict__ F1,
    float2* __restrict__ P2) {
  __shared__ __align__(16) float img[50 * 52];          // 10.4 KB
  __shared__ __align__(16) float2 Arow[2][50 * PST];    // 42.4 KB
  const int tid = threadIdx.x;
  const int ab = blockIdx.x, a = ab / NB, b = ab % NB;
  float sa, ca; sincosf((float)a * ASTEP, &sa, &ca);

  for (int f = 0; f < 2; ++f) {
    const float* src = lig_comb + (b * 2 + f) * NPIX;
    for (int o = tid; o < 50 * 52; o += 256) {
      int i = o / 52, j = o - i * 52;
      float acc = 0.f;
      if (j < 50) {
        float gx = fmaf((float)j, 2.0f / 49.0f, -1.0f);
        float gy = fmaf((float)i, 2.0f / 49.0f, -1.0f);
        float ix = (ca * gx + sa * gy + 1.0f) * 24.5f;
        float iy = (ca * gy - sa * gx + 1.0f) * 24.5f;
        float x0 = floorf(ix), y0 = floorf(iy);
#pragma unroll
        for (int dy = 0; dy < 2; ++dy)
#pragma unroll
          for (int dx = 0; dx < 2; ++dx) {
            float xc = x0 + dx, yc = y0 + dy;
            float w = (1.0f - fabsf(ix - xc)) * (1.0f - fabsf(iy - yc));
            bool valid = (xc >= 0.f) && (xc < 50.f) && (yc >= 0.f) && (yc < 50.f);
            int xi = (int)fminf(fmaxf(xc, 0.f), 49.f);
            int yi = (int)fminf(fmaxf(yc, 0.f), 49.f);
            acc += valid ? w * src[yi * L + xi] : 0.f;
          }
      }
      img[o] = acc;
    }
    __syncthreads();
    rowdft53(img, Arow[f], tid);
    __syncthreads();
  }

  // colDFT + product, 2 passes x 250 lanes, W=6 (phase-local 48-float accs)
  for (int pass = 0; pass < 2; ++pass) {
    if (tid < 250) {
      const int v = pass * 250 + tid;
      const int mp = v % 50, c = v / 50;
      const int k0 = 5 * c;
      float E0x[6], E0y[6], O0x[6], O0y[6];
      float E1x[6], E1y[6], O1x[6], O1y[6];
#pragma unroll
      for (int i = 0; i < 6; ++i) {
        E0x[i] = 0.f; E0y[i] = 0.f; O0x[i] = 0.f; O0y[i] = 0.f;
        E1x[i] = 0.f; E1y[i] = 0.f; O1x[i] = 0.f; O1y[i] = 0.f;
      }
      float s2x, s2y;
      sincosf(PHI * (float)((2 * mp) % 100), &s2y, &s2x); s2y = -s2y;
      { float wx = 1.f, wy = 0.f;           // even rows
        for (int s = 0; s < 25; ++s) {
          const float2* a0 = &Arow[0][(2 * s) * PST + k0];
          const float2* a1 = &Arow[1][(2 * s) * PST + k0];
#pragma unroll
          for (int i = 0; i < 6; ++i) {
            float2 q0 = a0[i], q1 = a1[i];
            E0x[i] = fmaf(q0.x, wx, fmaf(-q0.y, wy, E0x[i]));
            E0y[i] = fmaf(q0.x, wy, fmaf( q0.y, wx, E0y[i]));
            E1x[i] = fmaf(q1.x, wx, fmaf(-q1.y, wy, E1x[i]));
            E1y[i] = fmaf(q1.x, wy, fmaf( q1.y, wx, E1y[i]));
          }
          CROT(wx, wy, s2x, s2y);
        } }
      { float wx, wy;                       // odd rows
        sincosf(PHI * (float)mp, &wy, &wx); wy = -wy;
        for (int s = 0; s < 25; ++s) {
          const float2* a0 = &Arow[0][(2 * s + 1) * PST + k0];
          const float2* a1 = &Arow[1][(2 * s + 1) * PST + k0];
#pragma unroll
          for (int i = 0; i < 6; ++i) {
            float2 q0 = a0[i], q1 = a1[i];
            O0x[i] = fmaf(q0.x, wx, fmaf(-q0.y, wy, O0x[i]));
            O0y[i] = fmaf(q0.x, wy, fmaf( q0.y, wx, O0y[i]));
            O1x[i] = fmaf(q1.x, wx, fmaf(-q1.y, wy, O1x[i]));
            O1y[i] = fmaf(q1.x, wy, fmaf( q1.y, wx, O1y[i]));
          }
          CROT(wx, wy, s2x, s2y);
        } }
      const float2* F0a = F1 + (size_t)(b * 2 + 0) * ISPEC + mp * IST + k0;
      const float2* F0b = F0a + 50 * IST;
      const float2* F1a = F1 + (size_t)(b * 2 + 1) * ISPEC + mp * IST + k0;
      const float2* F1b = F1a + 50 * IST;
      float2 tmp[12];
#pragma unroll
      for (int i = 0; i < 6; ++i) {
        float gm0x = E0x[i] + O0x[i], gm0y = E0y[i] + O0y[i];
        float gp0x = E0x[i] - O0x[i], gp0y = E0y[i] - O0y[i];
        float gm1x = E1x[i] + O1x[i], gm1y = E1y[i] + O1y[i];
        float gp1x = E1x[i] - O1x[i], gp1y = E1y[i] - O1y[i];
        float2 A0 = F0a[i], B0 = F0b[i], A1 = F1a[i], B1 = F1b[i];
        tmp[i] = make_float2(
            fmaf(A0.x, gm0x, fmaf(A0.y, gm0y, fmaf(A1.x, gm1x, A1.y * gm1y))),
            fmaf(A0.y, gm0x, fmaf(-A0.x, gm0y, fmaf(A1.y, gm1x, -A1.x * gm1y))));
        tmp[6 + i] = make_float2(
            fmaf(B0.x, gp0x, fmaf(B0.y, gp0y, fmaf(B1.x, gp1x, B1.y * gp1y))),
            fmaf(B0.y, gp0x, fmaf(-B0.x, gp0y, fmaf(B1.y, gp1x, -B1.x * gp1y))));
      }
      float4* dst = (float4*)(P2 + (size_t)ab * 6000 + v * 12);
#pragma unroll
      for (int j = 0; j < 6; ++j)
        dst[j] = make_float4(tmp[2 * j].x, tmp[2 * j].y, tmp[2 * j + 1].x, tmp[2 * j + 1].y);
    }
  }
}

// ---------------- inverse (radix-2 both stages) + fftshift + argmax --------
// R7-verified no-spill version: 200-lane stages, compile-time-width
// unconditional accumulate loops, predication only at write boundaries.
__global__ __launch_bounds__(256, 3) void k_inv_argmax(
    const float2* __restrict__ P2, float* __restrict__ pval,
    int* __restrict__ pidx) {
  __shared__ __align__(16) float2 Pl[100 * PST];   // P[m][k]; later T[k][100]
  __shared__ float rv[256];
  __shared__ int ri[256];
  const int tid = threadIdx.x, ab = blockIdx.x;

  // un-pack packed P into Pl[m*PST + k]
  if (tid < 250) {
#pragma unroll
    for (int h = 0; h < 2; ++h) {
      int v = h * 250 + tid;
      int mp = v % 50, c = v / 50, k0p = 5 * c;
      const float4* s4 = (const float4*)(P2 + (size_t)ab * 6000 + v * 12);
      float2 tv[12];
#pragma unroll
      for (int j = 0; j < 6; ++j) {
        float4 q = s4[j];
        tv[2 * j] = make_float2(q.x, q.y);
        tv[2 * j + 1] = make_float2(q.z, q.w);
      }
#pragma unroll
      for (int i = 0; i < 6; ++i) {
        Pl[mp * PST + k0p + i] = tv[i];
        Pl[(mp + 50) * PST + k0p + i] = tv[6 + i];
      }
    }
  }
  __syncthreads();

  // stage 1: T[r][k] = sum_m P[m][k] e^{+i*PHI*m*r}; radix-2 pairs (r, r+50)
  const int rp = tid % 50, kc = tid / 50;
  const int k0 = (kc < 2) ? kc * 14 : 28 + (kc - 2) * 12;
  const int CW = (kc < 2) ? 14 : 12;
  float Ex[14], Ey[14], Ox[14], Oy[14];
  if (tid < 200) {
#pragma unroll
    for (int i = 0; i < 14; ++i) { Ex[i] = 0.f; Ey[i] = 0.f; Ox[i] = 0.f; Oy[i] = 0.f; }
    float stx, sty;
    sincosf(PHI * (float)((2 * rp) % 100), &sty, &stx);   // step e^{+2i phi r}
    { float wx = 1.f, wy = 0.f;
      for (int s = 0; s < 50; ++s) {
        if (s == 25) { wx = (rp & 1) ? -1.f : 1.f; wy = 0.f; }   // exact renorm
        const float2* pp = Pl + (2 * s) * PST + k0;
#pragma unroll
        for (int i = 0; i < 14; ++i) {
          float2 q = pp[i];
          Ex[i] = fmaf(q.x, wx, fmaf(-q.y, wy, Ex[i]));
          Ey[i] = fmaf(q.x, wy, fmaf( q.y, wx, Ey[i]));
        }
        CROT(wx, wy, stx, sty);
      } }
    { float wx, wy;
      sincosf(PHI * (float)rp, &wy, &wx);                  // e^{+i phi r}
      for (int s = 0; s < 50; ++s) {
        if (s == 25) { int t0 = (51 * rp) % 100; sincosf(PHI * (float)t0, &wy, &wx); }
        const float2* pp = Pl + (2 * s + 1) * PST + k0;
#pragma unroll
        for (int i = 0; i < 14; ++i) {
          float2 q = pp[i];
          Ox[i] = fmaf(q.x, wx, fmaf(-q.y, wy, Ox[i]));
          Oy[i] = fmaf(q.x, wy, fmaf( q.y, wx, Oy[i]));
        }
        CROT(wx, wy, stx, sty);
      } }
  }
  __syncthreads();   // all P reads complete
  if (tid < 200) {
#pragma unroll
    for (int i = 0; i < 14; ++i)
      if (i < CW && k0 + i < 51) {
        int k = k0 + i;
        Pl[k * NFULL + rp]      = make_float2(Ex[i] + Ox[i], Ey[i] + Oy[i]);
        Pl[k * NFULL + rp + 50] = make_float2(Ex[i] - Ox[i], Ey[i] - Oy[i]);
      }
  }
  __syncthreads();   // T[k][r] ready (transposed)

  // stage 2: radix-2 pairs (c, c+50) via even/odd k. Thread (cp, rc).
  float best = -3.4e38f;
  int bidx = 0x7fffffff;
  if (tid < 200) {
    const int cp = tid % 50, rc = tid / 50;
    const int r0 = (rc < 2) ? rc * 26 : 52 + (rc - 2) * 24;   // 16B-aligned
    const int RW = (rc < 2) ? 26 : 24;
    float e[26], o[26];
#pragma unroll
    for (int i = 0; i < 26; ++i) { e[i] = 0.f; o[i] = 0.f; }
    float stx, sty;
    sincosf(PHI * (float)((2 * cp) % 100), &sty, &stx);       // step e^{+2i phi c}
    { float wx = stx, wy = sty;                               // k=2 start
      for (int s = 1; s < 25; ++s) {
        const float2* tp = Pl + (2 * s) * NFULL + r0;
#pragma unroll
        for (int i = 0; i < 26; ++i) {
          float2 q = tp[i];
          e[i] = fmaf(q.x, wx, fmaf(-q.y, wy, e[i]));
        }
        CROT(wx, wy, stx, sty);
      } }
    { float wx, wy;
      sincosf(PHI * (float)cp, &wy, &wx);                     // k=1 start
      for (int s = 0; s < 25; ++s) {
        const float2* tp = Pl + (2 * s + 1) * NFULL + r0;
#pragma unroll
        for (int i = 0; i < 26; ++i) {
          float2 q = tp[i];
          o[i] = fmaf(q.x, wx, fmaf(-q.y, wy, o[i]));
        }
        CROT(wx, wy, stx, sty);
      } }
    float sgn = (cp & 1) ? -1.f : 1.f;
    const float2* T0  = Pl + r0;
    const float2* T50 = Pl + 50 * NFULL + r0;
    const int ys0 = cp + 50, ys1 = cp;
#pragma unroll
    for (int i = 0; i < 26; ++i)
      if (i < RW) {
        int r = r0 + i;
        float base = T0[i].x + sgn * T50[i].x;
        float X0 = fmaf(2.f, e[i] + o[i], base);   // c = cp
        float X1 = fmaf(2.f, e[i] - o[i], base);   // c = cp + 50
        int xs = r + 50; if (xs >= 100) xs -= 100;
        int f0 = xs * 100 + ys0, f1 = xs * 100 + ys1;
        if (X0 > best || (X0 == best && f0 < bidx)) { best = X0; bidx = f0; }
        if (X1 > best || (X1 == best && f1 < bidx)) { best = X1; bidx = f1; }
      }
  }
  rv[tid] = best; ri[tid] = bidx;
  __syncthreads();
  for (int s = 128; s > 0; s >>= 1) {
    if (tid < s) {
      float ov = rv[tid + s]; int oi = ri[tid + s];
      if (ov > rv[tid] || (ov == rv[tid] && oi < ri[tid])) { rv[tid] = ov; ri[tid] = oi; }
    }
    __syncthreads();
  }
  if (tid == 0) { pval[ab] = rv[0]; pidx[ab] = (ab / NB) * 10000 + ri[0]; }
}

// ---------------- final per-batch reduction over 120 angles ----------------
__global__ void k_final(const float* __restrict__ pval,
                        const int* __restrict__ pidx, float* __restrict__ out) {
  int b = threadIdx.x;
  if (b >= NB) return;
  float best = -3.4e38f; int bidx = 0x7fffffff;
  for (int a = 0; a < NA; ++a) {
    float v = pval[a * NB + b]; int ix = pidx[a * NB + b];
    if (v > best || (v == best && ix < bidx)) { best = v; bidx = ix; }
  }
  int a = bidx / 10000, rr = bidx % 10000, x = rr / NFULL, y = rr % NFULL;
  out[b] = a * ASTEP;
  out[NB + b * 2 + 0] = (float)(x - L);
  out[NB + b * 2 + 1] = (float)(y - L);
}

extern "C" void kernel_launch(void* const* d_in, const int* in_sizes, int n_in,
                              void* d_out, int out_size, void* d_ws, size_t ws_size,
                              hipStream_t stream) {
  const float* receptor = (const float*)d_in[0];
  const float* ligand   = (const float*)d_in[1];
  const float* conv_w   = (const float*)d_in[2];
  const float* conv_b   = (const float*)d_in[3];
  const float* scorer_w = (const float*)d_in[4];
  // scorer_b (d_in[5]) is argmax-invariant: unused.
  float* ws = (float*)d_ws;
  float* rec_feat = ws + OFF_REC;
  float* lig_comb = ws + OFF_LIG;
  float2* F1      = (float2*)(ws + OFF_F1);
  float2* P2      = (float2*)(ws + OFF_P2);
  float* pval     = ws + OFF_PVAL;
  int*   pidx     = (int*)(ws + OFF_PIDX);
  float* out      = (float*)d_out;

  k_conv<<<(NB * NPIX + 255) / 256, 256, 0, stream>>>(
      receptor, ligand, conv_w, conv_b, scorer_w, rec_feat, lig_comb);
  k_fwd_rec<<<80, 256, 0, stream>>>(rec_feat, F1);
  k_fwd_prod<<<NA * NB, 256, 0, stream>>>(lig_comb, F1, P2);
  k_inv_argmax<<<NA * NB, 256, 0, stream>>>(P2, pval, pidx);
  k_final<<<1, 64, 0, stream>>>(pval, pidx, out);
}